// Round 11
// baseline (582.365 us; speedup 1.0000x reference)
//
#include <hip/hip_runtime.h>
#include <math.h>

#define LSEQ 1024
#define NB 64

typedef __attribute__((ext_vector_type(4))) float f32x4;
typedef __attribute__((ext_vector_type(8))) short bf16x8;
typedef __attribute__((ext_vector_type(4))) unsigned short u16x4;

__device__ __forceinline__ unsigned short f2bf(float x) {
    union { float f; unsigned int u; } a; a.f = x;
    unsigned int r = a.u + 0x7FFFu + ((a.u >> 16) & 1u);
    return (unsigned short)(r >> 16);
}
__device__ __forceinline__ float bf2f(unsigned short h) {
    union { float f; unsigned int u; } a; a.u = ((unsigned int)h) << 16;
    return a.f;
}
__device__ __forceinline__ float sigmoidf_(float x) { return 1.0f / (1.0f + __expf(-x)); }
__device__ __forceinline__ float seluf_(float x) {
    const float sc = 1.0507009873554805f, al = 1.6732632423543772f;
    return x > 0.0f ? sc * x : sc * al * (__expf(x) - 1.0f);
}
__device__ __forceinline__ void gload16(const unsigned short* g, unsigned short* l) {
    __builtin_amdgcn_global_load_lds(
        (const __attribute__((address_space(1))) unsigned int*)g,
        (__attribute__((address_space(3))) unsigned int*)l, 16, 0, 0);
}

// W (K x N fp32, N = 2*128*kw) -> Wt rows np = dir*128kw + (h>>5)*32kw + j*32 + (h&31)
__global__ __launch_bounds__(256) void conv_wt(const float* __restrict__ W,
                                               unsigned short* __restrict__ Wt,
                                               int K, int N, int kw) {
    int idx = blockIdx.x * 256 + threadIdx.x;
    if (idx >= K * N) return;
    int k = idx / N, n = idx - k * N;
    const int dir = n / (128 * kw);
    const int rem = n - dir * 128 * kw;
    const int h = rem / kw, j = rem - h * kw;
    const int np = dir * (128 * kw) + (h >> 5) * (32 * kw) + j * 32 + (h & 31);
    Wt[(size_t)np * K + k] = f2bf(W[idx]);
}

// input (L,B,128) fp32 -> inputT (B,L,128) bf16
__global__ __launch_bounds__(256) void conv_in_t(const float* __restrict__ in,
                                                 unsigned short* __restrict__ outp) {
    const int idx = blockIdx.x * 256 + threadIdx.x;  // (b, t, d4)
    const int d4 = idx & 31;
    const int t = (idx >> 5) & 1023;
    const int b = idx >> 15;
    const float4 v = *reinterpret_cast<const float4*>(&in[((size_t)t * NB + b) * 128 + d4 * 4]);
    u16x4 w;
    w[0] = f2bf(v.x); w[1] = f2bf(v.y); w[2] = f2bf(v.z); w[3] = f2bf(v.w);
    *(u16x4*)(&outp[((size_t)b * LSEQ + t) * 128 + d4 * 4]) = w;
}

// ---- fused SRU layer v8: block = (b, dir, hc) owning 32 channels x full L.
// Per 32-t chunk: MFMA GEMM (U -> LDS only), gates, serial c-chain (half-wave),
// outputs. 512 blocks; LDS <=62KB -> 2-3 blocks/CU. A-frag loads hoisted.
template <int KW, int K, bool XP_FROM_U, bool ACC>
__global__ __launch_bounds__(256) void fused_v8(const unsigned short* __restrict__ A,
                                                const unsigned short* __restrict__ Bt,
                                                const float* __restrict__ bias,
                                                unsigned short* __restrict__ Xout,
                                                float* __restrict__ feats) {
    constexpr int WC = 32 * KW;   // block cols (KW planes x 32 channels)
    constexpr int WCp = WC + 4;   // f32 row stride in Ulds
    constexpr int CF = WC / 16;   // col-frags (6 or 8)
    constexpr int NT = K / 64;
    __shared__ __align__(16) unsigned short smB[WC * K];
    __shared__ __align__(16) float Ulds[32 * WCp];

    const int bid = blockIdx.x;
    const int b = bid >> 3, dir = (bid >> 2) & 1, hc = bid & 3;
    const int n0 = dir * (128 * KW) + hc * (32 * KW);
    const int chbase = dir * 128 + hc * 32;  // global channel base in X (256-wide)

    const int tid = threadIdx.x;
    const int w = tid >> 6, l = tid & 63;
    const int rlo = l & 15, g = l >> 4;
    const int kswz = (rlo & 7) * 8;
    const int ch = tid & 31, tq = tid >> 5;  // S1/S3 indexing: 8 tq x 4 steps

    const float bfb = bias[dir * 128 + hc * 32 + ch];
    const float brb = bias[256 + dir * 128 + hc * 32 + ch];

    // ---- B resident (once): pre-swizzled source, linear LDS dest ----
#pragma unroll
    for (int kt = 0; kt < NT; ++kt)
#pragma unroll
        for (int cc = 0; cc < WC / 32; ++cc) {
            const int col = cc * 32 + (tid >> 3);
            const int kxb = (tid & 7) ^ ((tid >> 3) & 7);
            gload16(Bt + (size_t)(n0 + col) * K + kt * 64 + kxb * 8,
                    &smB[kt * (WC * 64) + cc * 2048 + tid * 8]);
        }
    __syncthreads();

    float c = 0.0f;      // recurrence state (wave0 lanes 0..31 = channels)
    float psum = 0.0f;

    for (int ci = 0; ci < 32; ++ci) {
        const int t0c = dir ? (LSEQ - 32 * (ci + 1)) : 32 * ci;
        const unsigned short* gA = A + ((size_t)b * LSEQ + t0c) * K;

        // ---- GEMM chunk: 32 rows x WC cols; A-frags hoisted (one latency) ----
        {
            bf16x8 af[NT][2][2];
#pragma unroll
            for (int kt = 0; kt < NT; ++kt)
#pragma unroll
                for (int mf = 0; mf < 2; ++mf)
#pragma unroll
                    for (int kk = 0; kk < 2; ++kk)
                        af[kt][mf][kk] = *(const bf16x8*)(gA + (size_t)(mf * 16 + rlo) * K +
                                                          kt * 64 + kk * 32 + g * 8);
            // r = 0: col-frag w
            {
                f32x4 acc0[2] = {(f32x4){0.f,0.f,0.f,0.f}, (f32x4){0.f,0.f,0.f,0.f}};
                const int colf = w * 16 + rlo;
#pragma unroll
                for (int kt = 0; kt < NT; ++kt)
#pragma unroll
                    for (int kk = 0; kk < 2; ++kk) {
                        const int koff = (kk * 32 + g * 8) ^ kswz;
                        const bf16x8 bff =
                            *(const bf16x8*)(&smB[kt * (WC * 64) + colf * 64 + koff]);
#pragma unroll
                        for (int mf = 0; mf < 2; ++mf)
                            acc0[mf] = __builtin_amdgcn_mfma_f32_16x16x32_bf16(
                                bff, af[kt][mf][kk], acc0[mf], 0, 0, 0);
                    }
#pragma unroll
                for (int mf = 0; mf < 2; ++mf)
                    *(f32x4*)(&Ulds[(mf * 16 + rlo) * WCp + w * 16 + g * 4]) = acc0[mf];
            }
            // r = 1: col-frag w+4 (wave-uniform condition)
            if (w + 4 < CF) {
                f32x4 acc1[2] = {(f32x4){0.f,0.f,0.f,0.f}, (f32x4){0.f,0.f,0.f,0.f}};
                const int colf = (w + 4) * 16 + rlo;
#pragma unroll
                for (int kt = 0; kt < NT; ++kt)
#pragma unroll
                    for (int kk = 0; kk < 2; ++kk) {
                        const int koff = (kk * 32 + g * 8) ^ kswz;
                        const bf16x8 bff =
                            *(const bf16x8*)(&smB[kt * (WC * 64) + colf * 64 + koff]);
#pragma unroll
                        for (int mf = 0; mf < 2; ++mf)
                            acc1[mf] = __builtin_amdgcn_mfma_f32_16x16x32_bf16(
                                bff, af[kt][mf][kk], acc1[mf], 0, 0, 0);
                    }
#pragma unroll
                for (int mf = 0; mf < 2; ++mf)
                    *(f32x4*)(&Ulds[(mf * 16 + rlo) * WCp + (w + 4) * 16 + g * 4]) = acc1[mf];
            }
        }
        __syncthreads();

        // ---- S1: gates (parallel). planes: 0=u0->g, 1=u1->f, 2=u2->r, [3=xp] ----
#pragma unroll
        for (int ii = 0; ii < 4; ++ii) {
            const int lt = tq * 4 + ii;
            const float u0 = Ulds[lt * WCp + ch];
            const float u1 = Ulds[lt * WCp + 32 + ch];
            const float u2 = Ulds[lt * WCp + 64 + ch];
            const float f = sigmoidf_(u1 + bfb);
            const float r = sigmoidf_(u2 + brb);
            Ulds[lt * WCp + ch] = (1.0f - f) * u0;  // g
            Ulds[lt * WCp + 32 + ch] = f;
            Ulds[lt * WCp + 64 + ch] = r;
        }
        __syncthreads();

        // ---- chain: wave0 lanes 0..31 (lane = channel) ----
        if (w == 0 && l < 32) {
            float fv[32], gv[32];
#pragma unroll
            for (int j = 0; j < 32; ++j) {
                fv[j] = Ulds[j * WCp + 32 + l];
                gv[j] = Ulds[j * WCp + l];
            }
            if (dir == 0) {
#pragma unroll
                for (int j = 0; j < 32; ++j) {
                    c = fmaf(fv[j], c, gv[j]);
                    Ulds[j * WCp + l] = c;
                }
            } else {
#pragma unroll
                for (int j = 31; j >= 0; --j) {
                    c = fmaf(fv[j], c, gv[j]);
                    Ulds[j * WCp + l] = c;
                }
            }
        }
        __syncthreads();

        // ---- S3: outputs (parallel) ----
#pragma unroll
        for (int ii = 0; ii < 4; ++ii) {
            const int lt = tq * 4 + ii;
            const int t = t0c + lt;
            const float cv = Ulds[lt * WCp + ch];
            const float r = Ulds[lt * WCp + 64 + ch];
            float xp;
            if constexpr (XP_FROM_U)
                xp = Ulds[lt * WCp + 96 + ch];
            else
                xp = bf2f(A[((size_t)b * LSEQ + t) * K + chbase + ch]);
            const float ho = r * seluf_(cv) + (1.0f - r) * xp;
            if constexpr (ACC)
                psum += ho;
            else
                Xout[((size_t)b * LSEQ + t) * 256 + chbase + ch] = f2bf(ho);
        }
        __syncthreads();  // Ulds free for next chunk
    }

    if constexpr (ACC) {
        Ulds[tq * 32 + ch] = psum;
        __syncthreads();
        if (tid < 32) {
            float s = 0.0f;
#pragma unroll
            for (int i = 0; i < 8; ++i) s += Ulds[i * 32 + tid];
            feats[b * 256 + chbase + tid] = s * (1.0f / (float)LSEQ);
        }
    }
}

// layernorm over feats (B x 256 fp32)
__global__ __launch_bounds__(256) void ln_out(const float* __restrict__ feats,
                                              const float* __restrict__ gamma,
                                              const float* __restrict__ beta,
                                              float* __restrict__ out) {
    const int b = blockIdx.x, chn = threadIdx.x;
    const float feat = feats[b * 256 + chn];
    __shared__ float red[256];
    red[chn] = feat; __syncthreads();
    for (int off = 128; off > 0; off >>= 1) { if (chn < off) red[chn] += red[chn + off]; __syncthreads(); }
    const float mu = red[0] * (1.0f / 256.0f);
    __syncthreads();
    const float d = feat - mu;
    red[chn] = d * d; __syncthreads();
    for (int off = 128; off > 0; off >>= 1) { if (chn < off) red[chn] += red[chn + off]; __syncthreads(); }
    const float var = red[0] * (1.0f / 256.0f);
    out[b * 256 + chn] = d * rsqrtf(var + 1e-5f) * gamma[chn] + beta[chn];
}

extern "C" void kernel_launch(void* const* d_in, const int* in_sizes, int n_in,
                              void* d_out, int out_size, void* d_ws, size_t ws_size,
                              hipStream_t stream) {
    const float* input = (const float*)d_in[0];
    const float* gamma = (const float*)d_in[3];
    const float* beta  = (const float*)d_in[4];
    const float* Wl[4] = { (const float*)d_in[1], (const float*)d_in[5],
                           (const float*)d_in[7], (const float*)d_in[9] };
    const float* bl[4] = { (const float*)d_in[2], (const float*)d_in[6],
                           (const float*)d_in[8], (const float*)d_in[10] };
    float* out = (float*)d_out;

    char* base = (char*)d_ws;
    size_t off = 0;
    auto alloc = [&](size_t bytes) { size_t o = off; off = (off + bytes + 255) & ~(size_t)255; return o; };

    unsigned short* Wt[4];
    Wt[0] = (unsigned short*)(base + alloc((size_t)1024 * 128 * 2));
    for (int i = 1; i < 4; ++i) Wt[i] = (unsigned short*)(base + alloc((size_t)768 * 256 * 2));
    unsigned short* Xc = (unsigned short*)(base + alloc((size_t)NB * LSEQ * 128 * 2));  // inputT
    unsigned short* Xa = (unsigned short*)(base + alloc((size_t)NB * LSEQ * 256 * 2));
    unsigned short* Xb = (unsigned short*)(base + alloc((size_t)NB * LSEQ * 256 * 2));
    float* feats = (float*)(base + alloc((size_t)NB * 256 * 4));
    if (ws_size < off) return;

    conv_in_t<<<dim3(NB * LSEQ * 32 / 256), 256, 0, stream>>>(input, Xc);
    conv_wt<<<dim3((128 * 1024 + 255) / 256), 256, 0, stream>>>(Wl[0], Wt[0], 128, 1024, 4);
    for (int i = 1; i < 4; ++i)
        conv_wt<<<dim3((256 * 768 + 255) / 256), 256, 0, stream>>>(Wl[i], Wt[i], 256, 768, 3);

    fused_v8<4, 128, true, false><<<dim3(512), 256, 0, stream>>>(Xc, Wt[0], bl[0], Xa, nullptr);
    fused_v8<3, 256, false, false><<<dim3(512), 256, 0, stream>>>(Xa, Wt[1], bl[1], Xb, nullptr);
    fused_v8<3, 256, false, false><<<dim3(512), 256, 0, stream>>>(Xb, Wt[2], bl[2], Xa, nullptr);
    fused_v8<3, 256, false, true><<<dim3(512), 256, 0, stream>>>(Xa, Wt[3], bl[3], nullptr, feats);

    ln_out<<<dim3(NB), 256, 0, stream>>>(feats, gamma, beta, out);
}